// Round 3
// baseline (131.327 us; speedup 1.0000x reference)
//
#include <hip/hip_runtime.h>

// Problem constants (fixed by the reference):
//   B = 4194304 patches, each 2x2 f32  -> one float4 per patch
//   L = 5 affine-tanh layers, THRESHOLD = 0
#define B_TOTAL 4194304
#define NLAYER  5
#define NP      2      // patches per thread (small -> many waves -> latency hiding)
#define BLOCK   256

typedef float vfloat4 __attribute__((ext_vector_type(4)));  // native vector: OK for nontemporal builtins

__device__ __forceinline__ float fast_sigmoid(float z) {
    // 1/(1+exp(-z)); __expf -> v_exp_f32. Safe at extremes: exp(+inf)=inf -> 0, exp(-inf)=0 -> 1.
    return 1.0f / (1.0f + __expf(-z));
}

__device__ __forceinline__ float fast_tanh(float z) {
    // 1 - 2/(exp(2z)+1). Safe: z->+inf gives 1-0=1; z->-inf gives 1-2=-1. No inf/inf NaN.
    float t = __expf(2.0f * z);
    return 1.0f - 2.0f / (t + 1.0f);
}

__global__ __launch_bounds__(BLOCK) void fraud_kernel(
    const vfloat4* __restrict__ data,  // [B] patches as float4
    const float*  __restrict__ Wc,     // [4]
    const float*  __restrict__ bc,     // [1]
    const float*  __restrict__ Wl,     // [L*4]
    const float*  __restrict__ bl,     // [L*2]
    const float*  __restrict__ scale,  // [L*2]
    const float*  __restrict__ shift,  // [L*2]
    const float*  __restrict__ Wf,     // [2]
    const float*  __restrict__ bf,     // [1]
    float*        __restrict__ out)    // [B]
{
    // ---- Weights: wave-uniform loads -> compiler emits s_load into SGPRs ----
    const float4 wc = *(const float4*)Wc;
    const float  bcv = bc[0];

    float w[NLAYER][4], bb[NLAYER][2], sc[NLAYER][2], sh[NLAYER][2];
#pragma unroll
    for (int l = 0; l < NLAYER; ++l) {
        float4 wl = *(const float4*)(Wl + 4 * l);
        w[l][0] = wl.x; w[l][1] = wl.y; w[l][2] = wl.z; w[l][3] = wl.w;
        float2 b2 = *(const float2*)(bl + 2 * l);
        bb[l][0] = b2.x; bb[l][1] = b2.y;
        float2 s2 = *(const float2*)(scale + 2 * l);
        sc[l][0] = s2.x; sc[l][1] = s2.y;
        float2 h2 = *(const float2*)(shift + 2 * l);
        sh[l][0] = h2.x; sh[l][1] = h2.y;
    }
    const float2 wf = *(const float2*)Wf;
    const float  bfv = bf[0];

    const int tid    = blockIdx.x * BLOCK + threadIdx.x;
    const int stride = gridDim.x * BLOCK;

    // Issue both streaming loads up front (nontemporal: single-use data).
    vfloat4 d[NP];
#pragma unroll
    for (int k = 0; k < NP; ++k) {
        d[k] = __builtin_nontemporal_load(&data[tid + k * stride]);
    }

#pragma unroll
    for (int k = 0; k < NP; ++k) {
        const int i = tid + k * stride;    // coalesced across the wave

        // Conv2d(1,1,2) on 2x2 patch == dot4 + bias, then sigmoid
        float z = d[k].x * wc.x + d[k].y * wc.y + d[k].z * wc.z + d[k].w * wc.w + bcv;
        float x0 = fast_sigmoid(z);
        float x1 = 0.0f;

#pragma unroll
        for (int l = 0; l < NLAYER; ++l) {
            // x @ W.T + b  (W is [2,2], row-major)
            float y0 = fast_tanh(x0 * w[l][0] + x1 * w[l][1] + bb[l][0]) * sc[l][0] + sh[l][0];
            float y1 = fast_tanh(x0 * w[l][2] + x1 * w[l][3] + bb[l][1]) * sc[l][1] + sh[l][1];
            x0 = y0; x1 = y1;
        }

        __builtin_nontemporal_store(x0 * wf.x + x1 * wf.y + bfv, &out[i]);
    }
}

extern "C" void kernel_launch(void* const* d_in, const int* in_sizes, int n_in,
                              void* d_out, int out_size, void* d_ws, size_t ws_size,
                              hipStream_t stream) {
    const vfloat4* data = (const vfloat4*)d_in[0];
    const float*  Wc    = (const float*)d_in[1];
    const float*  bc    = (const float*)d_in[2];
    const float*  Wl    = (const float*)d_in[3];
    const float*  bl    = (const float*)d_in[4];
    const float*  scale = (const float*)d_in[5];
    const float*  shift = (const float*)d_in[6];
    const float*  Wf    = (const float*)d_in[7];
    const float*  bf    = (const float*)d_in[8];
    float* out = (float*)d_out;

    const int grid = B_TOTAL / (BLOCK * NP);   // 4194304 / 512 = 8192 blocks
    fraud_kernel<<<grid, BLOCK, 0, stream>>>(data, Wc, bc, Wl, bl, scale, shift, Wf, bf, out);
}

// Round 4
// 117.011 us; speedup vs baseline: 1.1224x; 1.1224x over previous
//
#include <hip/hip_runtime.h>

// Problem constants (fixed by the reference):
//   B = 4194304 patches, each 2x2 f32  -> one float4 per patch
//   L = 5 affine-tanh layers, THRESHOLD = 0
#define B_TOTAL 4194304
#define NLAYER  5
#define NP      8      // patches per thread; grid 2048 -> exactly 8 waves/SIMD, one pass
#define BLOCK   256

// Fast reciprocal: single v_rcp_f32 (~1 ulp). rcp(inf)=0, so saturation limits stay exact.
__device__ __forceinline__ float fast_rcp(float x) { return __builtin_amdgcn_rcpf(x); }

__device__ __forceinline__ float fast_sigmoid(float z) {
    // 1/(1+exp(-z)). z->-inf: exp=inf -> rcp=0. z->+inf: exp=0 -> 1.
    return fast_rcp(1.0f + __expf(-z));
}

__device__ __forceinline__ float fast_tanh(float z) {
    // 1 - 2/(exp(2z)+1). z->+inf: rcp(inf)=0 -> 1. z->-inf: rcp(1)=1 -> -1.
    return 1.0f - 2.0f * fast_rcp(__expf(2.0f * z) + 1.0f);
}

__global__ __launch_bounds__(BLOCK, 8) void fraud_kernel(
    const float4* __restrict__ data,   // [B] patches as float4
    const float*  __restrict__ Wc,     // [4]
    const float*  __restrict__ bc,     // [1]
    const float*  __restrict__ Wl,     // [L*4]
    const float*  __restrict__ bl,     // [L*2]
    const float*  __restrict__ scale,  // [L*2]
    const float*  __restrict__ shift,  // [L*2]
    const float*  __restrict__ Wf,     // [2]
    const float*  __restrict__ bf,     // [1]
    float*        __restrict__ out)    // [B]
{
    // ---- Weights: wave-uniform loads -> SGPRs ----
    const float4 wc = *(const float4*)Wc;
    const float  bcv = bc[0];

    float w[NLAYER][4], bb[NLAYER][2], sc[NLAYER][2], sh[NLAYER][2];
#pragma unroll
    for (int l = 0; l < NLAYER; ++l) {
        float4 wl = *(const float4*)(Wl + 4 * l);
        w[l][0] = wl.x; w[l][1] = wl.y; w[l][2] = wl.z; w[l][3] = wl.w;
        float2 b2 = *(const float2*)(bl + 2 * l);
        bb[l][0] = b2.x; bb[l][1] = b2.y;
        float2 s2 = *(const float2*)(scale + 2 * l);
        sc[l][0] = s2.x; sc[l][1] = s2.y;
        float2 h2 = *(const float2*)(shift + 2 * l);
        sh[l][0] = h2.x; sh[l][1] = h2.y;
    }
    const float2 wf = *(const float2*)Wf;
    const float  bfv = bf[0];

    const int tid    = blockIdx.x * BLOCK + threadIdx.x;
    const int stride = gridDim.x * BLOCK;   // 524288

#pragma unroll
    for (int k = 0; k < NP; ++k) {
        const int i = tid + k * stride;    // coalesced across the wave
        const float4 d = data[i];

        // Conv2d(1,1,2) on 2x2 patch == dot4 + bias, then sigmoid
        float z = d.x * wc.x + d.y * wc.y + d.z * wc.z + d.w * wc.w + bcv;
        float x0 = fast_sigmoid(z);
        float x1 = 0.0f;

#pragma unroll
        for (int l = 0; l < NLAYER; ++l) {
            // x @ W.T + b  (W is [2,2], row-major)
            float y0 = fast_tanh(x0 * w[l][0] + x1 * w[l][1] + bb[l][0]) * sc[l][0] + sh[l][0];
            float y1 = fast_tanh(x0 * w[l][2] + x1 * w[l][3] + bb[l][1]) * sc[l][1] + sh[l][1];
            x0 = y0; x1 = y1;
        }

        out[i] = x0 * wf.x + x1 * wf.y + bfv;
    }
}

extern "C" void kernel_launch(void* const* d_in, const int* in_sizes, int n_in,
                              void* d_out, int out_size, void* d_ws, size_t ws_size,
                              hipStream_t stream) {
    const float4* data  = (const float4*)d_in[0];
    const float*  Wc    = (const float*)d_in[1];
    const float*  bc    = (const float*)d_in[2];
    const float*  Wl    = (const float*)d_in[3];
    const float*  bl    = (const float*)d_in[4];
    const float*  scale = (const float*)d_in[5];
    const float*  shift = (const float*)d_in[6];
    const float*  Wf    = (const float*)d_in[7];
    const float*  bf    = (const float*)d_in[8];
    float* out = (float*)d_out;

    const int grid = B_TOTAL / (BLOCK * NP);   // 4194304 / 2048 = 2048 blocks
    fraud_kernel<<<grid, BLOCK, 0, stream>>>(data, Wc, bc, Wl, bl, scale, shift, Wf, bf, out);
}